// Round 1
// 911.616 us; speedup vs baseline: 1.1078x; 1.1078x over previous
//
#include <hip/hip_runtime.h>

// ---- problem constants ----
#define T_LEN   240
#define B_SZ    8
#define NFILT   2560
#define KD      9216          // 96*96
#define M_DIM   1920          // B*T
#define N_DIM   5120          // 2*NF (sin | cos)
#define PAD_L   8
#define KSPLIT  3
#define KSLICE  3072          // KD / KSPLIT
#define NT      96            // KSLICE / 32 k-tiles per block
#define GEMM_LDS 131072       // 2 dbuf x (Ah,Al,Bh,Bl)[256][32] bf16

typedef unsigned short u16;
typedef __attribute__((ext_vector_type(8)))  __bf16 bf16x8;
typedef __attribute__((ext_vector_type(16))) float  f32x16;

// ---------- fp32 -> (hi,lo) bf16 split, RNE both halves ----------
__device__ __forceinline__ u16 f2bf_rne(float f) {
    unsigned u = __float_as_uint(f);
    u += 0x7FFFu + ((u >> 16) & 1u);
    return (u16)(u >> 16);
}

__device__ __forceinline__ void split4(const float* __restrict__ src,
                                       u16* __restrict__ hi, u16* __restrict__ lo, int i) {
    const float4 v = ((const float4*)src)[i];
    float vv[4] = {v.x, v.y, v.z, v.w};
    u16 hh[4], ll[4];
#pragma unroll
    for (int j = 0; j < 4; ++j) {
        unsigned u = __float_as_uint(vv[j]);
        unsigned r = u + 0x7FFFu + ((u >> 16) & 1u);
        u16 hb = (u16)(r >> 16);
        float hf = __uint_as_float((unsigned)hb << 16);
        hh[j] = hb;
        ll[j] = f2bf_rne(vv[j] - hf);   // residual exact in fp32, then RNE
    }
    ushort4 h, l;
    h.x = hh[0]; h.y = hh[1]; h.z = hh[2]; h.w = hh[3];
    l.x = ll[0]; l.y = ll[1]; l.z = ll[2]; l.w = ll[3];
    ((ushort4*)hi)[i] = h;
    ((ushort4*)lo)[i] = l;
}

// one fused launch: x | w_sin | w_cos regions
#define NX4  (17694720 / 4)
#define NW4  (23592960 / 4)
__global__ void split_all_kernel(const float* __restrict__ x,
                                 const float* __restrict__ wss,
                                 const float* __restrict__ wsc,
                                 u16* __restrict__ xh, u16* __restrict__ xl,
                                 u16* __restrict__ wh, u16* __restrict__ wl) {
    int i = blockIdx.x * 256 + threadIdx.x;
    if (i < NX4) {
        split4(x, xh, xl, i);
    } else if (i < NX4 + NW4) {
        split4(wss, wh, wl, i - NX4);
    } else if (i < NX4 + 2 * NW4) {
        int j = i - NX4 - NW4;
        split4(wsc, wh + (size_t)NFILT * KD, wl + (size_t)NFILT * KD, j);
    }
}

// ---------- async global->LDS, 16B per lane ----------
__device__ __forceinline__ void glds16(const u16* gp, __bf16* lp) {
    __builtin_amdgcn_global_load_lds(
        (const __attribute__((address_space(1))) void*)gp,
        (__attribute__((address_space(3))) void*)lp, 16, 0, 0);
}

// swizzled element offset within a [256][32] bf16 tile.
// 16B granule index g of row r is XOR'd with (r>>1)&3 so each consecutive
// 8-lane ds_read_b128 group covers all eight 16B bank slots (zero conflict).
__device__ __forceinline__ int frag_off(int r, int fo) {
    return r * 32 + (((fo >> 3) ^ ((r >> 1) & 3)) << 3);
}

// ---------- bf16x3 split GEMM, 256x256 tile, 2-phase/k-tile deep pipeline ----
// C = Ah*Bh + Ah*Bl + Al*Bh   (32x32x16 MFMA, split-K=3, atomic accumulate)
__global__ __launch_bounds__(512, 2) void gemm_split_kernel(
    const u16* __restrict__ xh, const u16* __restrict__ xl,
    const u16* __restrict__ wh, const u16* __restrict__ wl,
    float* __restrict__ g) {

    extern __shared__ char smem_c[];
    __bf16* const smem = (__bf16*)smem_c;
    // per dbuf (32768 elems): Ah +0 | Al +8192 | Bh +16384 | Bl +24576
    // each tile [256][32] bf16 = 8192 elems, halves of 128 rows = 4096 elems

    const int tid = threadIdx.x;
    const int l   = tid & 63;
    const int w   = tid >> 6;

    // T1: bijective XCD swizzle (480 % 8 == 0)
    int bid = (int)blockIdx.x;
    bid = (bid & 7) * (160 * KSPLIT / 8) + (bid >> 3);
    const int ks = bid / 160;
    const int t  = bid % 160;
    const int m0 = (t / 20) * 256;       // 8 m-tiles (last is half-padded)
    const int n0 = (t % 20) * 256;       // 20 n-tiles
    const unsigned kb = (unsigned)ks * KSLICE;

    // ---- staging geometry: lane-linear LDS dest, inverse-swizzled source ----
    const int rl  = w * 16 + (l >> 2);                     // row within 128-row half
    const int gsw = ((l & 3) ^ ((rl >> 1) & 3)) * 8;       // swizzled source granule
    const int sd  = w * 512 + l * 8;                       // LDS elems, = base + lane*16B

    int ar0 = m0 + rl;        if (ar0 > M_DIM - 1) ar0 = M_DIM - 1;   // clamp pad rows
    int ar1 = m0 + rl + 128;  if (ar1 > M_DIM - 1) ar1 = M_DIM - 1;
    const unsigned offA0 = (unsigned)ar0 * KD + kb + gsw;
    const unsigned offA1 = (unsigned)ar1 * KD + kb + gsw;
    const unsigned offB0 = (unsigned)(n0 + rl) * KD + kb + gsw;
    const unsigned offB1 = (unsigned)(n0 + rl + 128) * KD + kb + gsw;

// chunk0: all of B (hi+lo) + A half0 (hi+lo) -> read in phase 1 of next k-tile
#define STAGE_CHUNK0(D, KOFF) do {                                   \
        __bf16* sb_ = smem + (D) * 32768;                            \
        glds16(wh + (offB0 + (KOFF)), sb_ + 16384 + sd);             \
        glds16(wh + (offB1 + (KOFF)), sb_ + 20480 + sd);             \
        glds16(wl + (offB0 + (KOFF)), sb_ + 24576 + sd);             \
        glds16(wl + (offB1 + (KOFF)), sb_ + 28672 + sd);             \
        glds16(xh + (offA0 + (KOFF)), sb_ + 0     + sd);             \
        glds16(xl + (offA0 + (KOFF)), sb_ + 8192  + sd);             \
    } while (0)
// chunk1: A half1 (hi+lo) -> read in phase 2
#define STAGE_CHUNK1(D, KOFF) do {                                   \
        __bf16* sb_ = smem + (D) * 32768;                            \
        glds16(xh + (offA1 + (KOFF)), sb_ + 4096  + sd);             \
        glds16(xl + (offA1 + (KOFF)), sb_ + 12288 + sd);             \
    } while (0)

    // ---- compute geometry: 8 waves = 2M x 4N; per-wave C = 128x64 ----
    // wave wr: phase p computes global rows [p*128 + wr*64, +64)
    const int rA = l & 31;
    const int kq = (l >> 5) * 8;
    const int wr = w >> 2;
    const int wc = w & 3;

    int aoff0[2][2], aoff1[2][2], boff[2][2];
#pragma unroll
    for (int mf = 0; mf < 2; ++mf)
#pragma unroll
        for (int sb2 = 0; sb2 < 2; ++sb2) {
            const int fo = sb2 * 16 + kq;
            aoff0[mf][sb2] = frag_off(wr * 64 + mf * 32 + rA, fo);
            aoff1[mf][sb2] = aoff0[mf][sb2] + 128 * 32;
            boff[mf][sb2]  = frag_off(wc * 64 + mf * 32 + rA, fo);
        }

    f32x16 acc[4][2];
#pragma unroll
    for (int i = 0; i < 4; ++i)
#pragma unroll
        for (int j = 0; j < 2; ++j)
#pragma unroll
            for (int r = 0; r < 16; ++r)
                acc[i][j][r] = 0.f;

#define MFMA3(ACC, AH, AL, BH, BL)                                              \
    ACC = __builtin_amdgcn_mfma_f32_32x32x16_bf16(AH, BH, ACC, 0, 0, 0);        \
    ACC = __builtin_amdgcn_mfma_f32_32x32x16_bf16(AH, BL, ACC, 0, 0, 0);        \
    ACC = __builtin_amdgcn_mfma_f32_32x32x16_bf16(AL, BH, ACC, 0, 0, 0);

    // ---- prologue: stage k-tile 0 into buf0 ----
    STAGE_CHUNK0(0, 0);
    STAGE_CHUNK1(0, 0);
    asm volatile("s_waitcnt vmcnt(2)" ::: "memory");   // chunk0 landed
    __builtin_amdgcn_s_barrier();

    for (int kt = 0; kt < NT; ++kt) {
        const int cur = kt & 1;
        const __bf16* sb = smem + cur * 32768;
        const int koff = (kt + 1) * 32;

        // ================= phase 1: rows [wr*64, +64) =================
        if (kt < NT - 1) STAGE_CHUNK0(cur ^ 1, koff);      // 6 glds in flight
        bf16x8 bhf[2][2], blf[2][2], ahf[2][2], alf[2][2];
#pragma unroll
        for (int nf = 0; nf < 2; ++nf)
#pragma unroll
            for (int s = 0; s < 2; ++s) {
                bhf[nf][s] = *(const bf16x8*)(sb + 16384 + boff[nf][s]);
                blf[nf][s] = *(const bf16x8*)(sb + 24576 + boff[nf][s]);
            }
#pragma unroll
        for (int mf = 0; mf < 2; ++mf)
#pragma unroll
            for (int s = 0; s < 2; ++s) {
                ahf[mf][s] = *(const bf16x8*)(sb + aoff0[mf][s]);
                alf[mf][s] = *(const bf16x8*)(sb + 8192 + aoff0[mf][s]);
            }
        __builtin_amdgcn_s_barrier();
        asm volatile("s_waitcnt lgkmcnt(0)" ::: "memory");
        __builtin_amdgcn_sched_barrier(0);
        __builtin_amdgcn_s_setprio(1);
#pragma unroll
        for (int mf = 0; mf < 2; ++mf)
#pragma unroll
            for (int nf = 0; nf < 2; ++nf)
#pragma unroll
                for (int s = 0; s < 2; ++s) {
                    MFMA3(acc[mf][nf], ahf[mf][s], alf[mf][s], bhf[nf][s], blf[nf][s]);
                }
        __builtin_amdgcn_s_setprio(0);
        if (kt < NT - 1) { asm volatile("s_waitcnt vmcnt(6)" ::: "memory"); }
        else             { asm volatile("s_waitcnt vmcnt(0)" ::: "memory"); }
        __builtin_amdgcn_s_barrier();

        // ================= phase 2: rows [128 + wr*64, +64) =================
        if (kt < NT - 1) STAGE_CHUNK1(cur ^ 1, koff);      // 2 more glds
#pragma unroll
        for (int mf = 0; mf < 2; ++mf)
#pragma unroll
            for (int s = 0; s < 2; ++s) {
                ahf[mf][s] = *(const bf16x8*)(sb + aoff1[mf][s]);
                alf[mf][s] = *(const bf16x8*)(sb + 8192 + aoff1[mf][s]);
            }
        __builtin_amdgcn_s_barrier();
        asm volatile("s_waitcnt lgkmcnt(0)" ::: "memory");
        __builtin_amdgcn_sched_barrier(0);
        __builtin_amdgcn_s_setprio(1);
#pragma unroll
        for (int mf = 0; mf < 2; ++mf)
#pragma unroll
            for (int nf = 0; nf < 2; ++nf)
#pragma unroll
                for (int s = 0; s < 2; ++s) {
                    MFMA3(acc[2 + mf][nf], ahf[mf][s], alf[mf][s], bhf[nf][s], blf[nf][s]);
                }
        __builtin_amdgcn_s_setprio(0);
        asm volatile("s_waitcnt vmcnt(2)" ::: "memory");   // chunk0(kt+1) landed
        __builtin_amdgcn_s_barrier();
    }

    // ---- epilogue: 32x32 C/D layout col=l&31, row=(r&3)+8*(r>>2)+4*(l>>5) ----
    const int cb = (l >> 5) * 4;
    const int cc = l & 31;
#pragma unroll
    for (int am = 0; am < 4; ++am) {
        const int rowb = m0 + (am >> 1) * 128 + wr * 64 + (am & 1) * 32;
        if (rowb < M_DIM) {                    // whole 32-row frag in/out (1920%32==0)
#pragma unroll
            for (int nf = 0; nf < 2; ++nf) {
                const int col = n0 + wc * 64 + nf * 32 + cc;
                float* gp = g + (size_t)rowb * N_DIM + col;
#pragma unroll
                for (int r = 0; r < 16; ++r) {
                    const int ro = (r & 3) + 8 * (r >> 2) + cb;
                    atomicAdd(gp + (size_t)ro * N_DIM, acc[am][nf][r]);
                }
            }
        }
    }
#undef STAGE_CHUNK0
#undef STAGE_CHUNK1
#undef MFMA3
}

// ---------- depthwise temporal conv + energy, LDS-staged weights ----------
// block = one (b, t, 256-filter chunk); thread = one filter.
__global__ __launch_bounds__(256) void conv_energy_kernel(
    const float* __restrict__ g,
    const float* __restrict__ wts,
    const float* __restrict__ wtc,
    float* __restrict__ out) {

    __shared__ float wl_c[16][256];
    __shared__ float wl_s[16][256];

    const int tid = threadIdx.x;
    const int bid = blockIdx.x;          // 19200 = 8 * 240 * 10
    const int fc  = bid % 10;
    const int t   = (bid / 10) % T_LEN;
    const int b   = bid / (10 * T_LEN);
    const int f0  = fc * 256;

    // cooperative weight load: thread tid owns filter f0+tid's 16 taps
    {
        const float4* wrc = (const float4*)(wtc + (size_t)(f0 + tid) * 16);
        const float4* wrs = (const float4*)(wts + (size_t)(f0 + tid) * 16);
#pragma unroll
        for (int k4 = 0; k4 < 4; ++k4) {
            const float4 vc = wrc[k4];
            const float4 vs = wrs[k4];
            wl_c[k4 * 4 + 0][tid] = vc.x; wl_c[k4 * 4 + 1][tid] = vc.y;
            wl_c[k4 * 4 + 2][tid] = vc.z; wl_c[k4 * 4 + 3][tid] = vc.w;
            wl_s[k4 * 4 + 0][tid] = vs.x; wl_s[k4 * 4 + 1][tid] = vs.y;
            wl_s[k4 * 4 + 2][tid] = vs.z; wl_s[k4 * 4 + 3][tid] = vs.w;
        }
    }
    __syncthreads();

    const float* grow = g + (size_t)b * T_LEN * N_DIM + f0 + tid;
    float s = 0.f, c = 0.f;
#pragma unroll
    for (int j = 0; j < 16; ++j) {
        const int tt = t + j - PAD_L;
        if (tt >= 0 && tt < T_LEN) {     // block-uniform branch (t fixed per block)
            const float gs = grow[(size_t)tt * N_DIM];
            const float gc = grow[(size_t)tt * N_DIM + NFILT];
            const float a  = wl_c[j][tid];
            const float bb = wl_s[j][tid];
            s += gs * a + gc * bb;
            c += gc * a - gs * bb;
        }
    }
    const float r = sqrtf(s * s + c * c);
    out[(size_t)((b * T_LEN + t) * NFILT) + f0 + tid] = logf(r + 1e-5f);
}

extern "C" void kernel_launch(void* const* d_in, const int* in_sizes, int n_in,
                              void* d_out, int out_size, void* d_ws, size_t ws_size,
                              hipStream_t stream) {
    const float* x   = (const float*)d_in[0];  // (8,240,96,96)
    const float* wss = (const float*)d_in[1];  // (2560,96,96)
    const float* wsc = (const float*)d_in[2];  // (2560,96,96)
    const float* wts = (const float*)d_in[3];  // (2560,16)
    const float* wtc = (const float*)d_in[4];  // (2560,16)
    float* out = (float*)d_out;

    // workspace layout (bytes):
    //   xh: 35,389,440 | xl: 35,389,440 | wh: 94,371,840 | wl: 94,371,840 | g: 39,321,600
    char* ws = (char*)d_ws;
    u16*   xh  = (u16*)(ws);
    u16*   xl  = (u16*)(ws + 35389440);
    u16*   whi = (u16*)(ws + 70778880);
    u16*   wlo = (u16*)(ws + 165150720);
    float* g   = (float*)(ws + 259522560);

    static bool gemm_attr_set = false;
    if (!gemm_attr_set) {
        hipFuncSetAttribute(reinterpret_cast<const void*>(gemm_split_kernel),
                            hipFuncAttributeMaxDynamicSharedMemorySize, GEMM_LDS);
        gemm_attr_set = true;
    }

    hipMemsetAsync(g, 0, (size_t)M_DIM * N_DIM * 4, stream);

    const int ntot4 = NX4 + 2 * NW4;
    split_all_kernel<<<(ntot4 + 255) / 256, 256, 0, stream>>>(x, wss, wsc, xh, xl, whi, wlo);

    gemm_split_kernel<<<160 * KSPLIT, 512, GEMM_LDS, stream>>>(xh, xl, whi, wlo, g);

    conv_energy_kernel<<<B_SZ * T_LEN * 10, 256, 0, stream>>>(g, wts, wtc, out);
}